// Round 1
// baseline (313.512 us; speedup 1.0000x reference)
//
#include <hip/hip_runtime.h>
#include <hip/hip_bf16.h>

typedef __hip_bfloat16 bf16;
typedef __attribute__((ext_vector_type(8))) short short8;
typedef __attribute__((ext_vector_type(4))) float f32x4;

#define S  3
#define V  25
#define C  64
#define O  64
#define IC 16
#define NN 32
#define TT 256
#define TB 2
#define TCH 32

__device__ __forceinline__ float b2f(bf16 v) { return __bfloat162float(v); }

__device__ __forceinline__ float ldv(const void* p, size_t i, int f32) {
    return f32 ? ((const float*)p)[i] : b2f(((const bf16*)p)[i]);
}

__device__ __forceinline__ unsigned short f2bf(float f) {
    bf16 h = __float2bfloat16(f);
    return *(unsigned short*)&h;
}

__device__ __forceinline__ void fma4(float4& a, float s, float4 b) {
    a.x += s * b.x; a.y += s * b.y; a.z += s * b.z; a.w += s * b.w;
}

__device__ __forceinline__ float dot16v(const float* a, const float* b) {
    float4 a0 = *(const float4*)(a + 0),  a1 = *(const float4*)(a + 4);
    float4 a2 = *(const float4*)(a + 8),  a3 = *(const float4*)(a + 12);
    float4 b0 = *(const float4*)(b + 0),  b1 = *(const float4*)(b + 4);
    float4 b2 = *(const float4*)(b + 8),  b3 = *(const float4*)(b + 12);
    float e = a0.x*b0.x + a0.y*b0.y + a0.z*b0.z + a0.w*b0.w;
    e += a1.x*b1.x + a1.y*b1.y + a1.z*b1.z + a1.w*b1.w;
    e += a2.x*b2.x + a2.y*b2.y + a2.z*b2.z + a2.w*b2.w;
    e += a3.x*b3.x + a3.y*b3.y + a3.z*b3.z + a3.w*b3.w;
    return e;
}

// ---------------------------------------------------------------------------
// k_detect: wave-parallel dtype sniff (was: 1 thread, 2048 serially-dependent
// loads ≈ 60-120 µs of pure load latency; now 64 lanes, no break, ~2 µs).
// Semantics identical: flag=1 iff ANY of the first 2048 bf16-interpreted
// values falls outside (-1000, 1000).
// ---------------------------------------------------------------------------
__global__ void k_detect(const void* __restrict__ x, int* __restrict__ flag) {
    const bf16* p = (const bf16*)x;
    int lane = threadIdx.x;
    int bad = 0;
    #pragma unroll
    for (int k = 0; k < 32; k++) {
        float v = b2f(p[lane + k * 64]);
        bad |= !(v > -1000.f && v < 1000.f);
    }
    unsigned long long m = __ballot(bad);
    if (lane == 0) *flag = (m != 0ull) ? 1 : 0;
}

// ---------------------------------------------------------------------------
// k_prep: zero S1; convert weights to bf16 transposed/padded MFMA layouts
// (wprep per s: [watb 16x72 | wbtb 16x72 | wdtb 64x72]); compute A_comb.
// ---------------------------------------------------------------------------
__global__ __launch_bounds__(256) void k_prep(
    const void* __restrict__ A, const void* __restrict__ PA,
    const void* __restrict__ wA,
    const void* __restrict__ Wa, const void* __restrict__ Wb,
    const void* __restrict__ Wd,
    float* __restrict__ A_comb, float* __restrict__ S1,
    unsigned short* __restrict__ wprep, const int* __restrict__ flagp) {
    int f32 = *flagp;
    int g = blockIdx.x * 256 + threadIdx.x;
    int stride = gridDim.x * 256;

    for (int w = g; w < 60000; w += stride) S1[w] = 0.f;

    for (int w = g; w < 3456; w += stride) {           // Wa/Wb -> [i][c] bf16
        int s = w / 1152, r = w % 1152, i = r / 72, c = r % 72;
        unsigned short va = 0, vb = 0;
        if (c < 64) {
            va = f2bf(ldv(Wa, (size_t)s * 1024 + c * 16 + i, f32));
            vb = f2bf(ldv(Wb, (size_t)s * 1024 + c * 16 + i, f32));
        }
        wprep[s * 6912 + i * 72 + c] = va;
        wprep[s * 6912 + 1152 + i * 72 + c] = vb;
    }
    for (int w = g; w < 13824; w += stride) {          // Wd -> [o][c] bf16
        int s = w / 4608, r = w % 4608, o = r / 72, c = r % 72;
        unsigned short vd = 0;
        if (c < 64) vd = f2bf(ldv(Wd, (size_t)s * 4096 + c * 64 + o, f32));
        wprep[s * 6912 + 2304 + o * 72 + c] = vd;
    }

    if (g < S * V) {                                    // A_comb rows
        float w0 = ldv(wA, 0, f32), w1 = ldv(wA, 1, f32);
        float vals[V];
        float m = -1e30f;
        for (int v = 0; v < V; v++) { vals[v] = ldv(PA, g * V + v, f32); m = fmaxf(m, vals[v]); }
        float sum = 0.f;
        for (int v = 0; v < V; v++) { vals[v] = __expf(vals[v] - m); sum += vals[v]; }
        float inv = 1.f / sum;
        for (int v = 0; v < V; v++)
            A_comb[g * V + v] = w0 * ldv(A, g * V + v, f32) + w1 * vals[v] * inv;
    }
}

// ---------------------------------------------------------------------------
// k_s1: S1[s,n,u,v] = sum_t qa . kb
//   round-1 changes: (a) bf16 staging vectorized (uint2 = 4x bf16 -> float4
//   LDS store; 800 loads/iter instead of 3200 scalar), (b) qa/kb projection
//   re-threaded to 200 threads (per (u,t,iq)), halving the per-thread FMA
//   chain. Dot phase and atomics unchanged (known-good).
// ---------------------------------------------------------------------------
__global__ __launch_bounds__(256) void k_s1(
    const void* __restrict__ x,
    const void* __restrict__ Wa, const void* __restrict__ ba,
    const void* __restrict__ Wb, const void* __restrict__ bb,
    float* __restrict__ S1g, const int* __restrict__ flagp) {
    int f32 = *flagp;
    int tchunk = blockIdx.x, n = blockIdx.y, s = blockIdx.z;
    int tid = threadIdx.x;

    __shared__ __align__(16) float xs[2][V][68];
    __shared__ __align__(16) float was[C][IC], wbs[C][IC];
    __shared__ __align__(16) float qa[2][V][20], kb[2][V][20];
    __shared__ __align__(16) float bas[IC], bbs[IC];

    if (f32) {
        const float4* Wa4 = (const float4*)Wa + s * 256;
        const float4* Wb4 = (const float4*)Wb + s * 256;
        if (tid < 256) { ((float4*)was)[tid] = Wa4[tid]; ((float4*)wbs)[tid] = Wb4[tid]; }
    } else {
        for (int w = tid; w < 1024; w += 256) {
            ((float*)was)[w] = ldv(Wa, (size_t)s * 1024 + w, 0);
            ((float*)wbs)[w] = ldv(Wb, (size_t)s * 1024 + w, 0);
        }
    }
    if (tid < IC) { bas[tid] = ldv(ba, s * IC + tid, f32); bbs[tid] = ldv(bb, s * IC + tid, f32); }

    float acc[2][2] = {{0.f, 0.f}, {0.f, 0.f}};
    int t0 = tchunk * TCH;
    for (int tt = 0; tt < TCH; tt += 2) {
        __syncthreads();
        if (f32) {
            const float4* xp = (const float4*)x + (size_t)(n * TT + t0 + tt) * 400;
            for (int w = tid; w < 800; w += 256) {
                int t = w / 400, r = w % 400;
                *(float4*)&xs[t][r >> 4][(r & 15) * 4] = xp[w];
            }
        } else {
            const uint2* xp = (const uint2*)x + (size_t)(n * TT + t0 + tt) * 400;
            for (int w = tid; w < 800; w += 256) {
                int t = w / 400, r = w % 400, u = r >> 4, c4 = r & 15;
                uint2 pk = xp[w];
                const bf16* h = (const bf16*)&pk;
                float4 f = {b2f(h[0]), b2f(h[1]), b2f(h[2]), b2f(h[3])};
                *(float4*)&xs[t][u][c4 * 4] = f;
            }
        }
        __syncthreads();
        if (tid < 200) {
            int u = tid >> 3, r = tid & 7, t = r >> 2, iq = r & 3;
            float4 aq = *(const float4*)&bas[iq * 4];
            float4 ak = *(const float4*)&bbs[iq * 4];
            #pragma unroll
            for (int c4 = 0; c4 < 16; c4++) {
                float4 xv = *(const float4*)&xs[t][u][c4 * 4];
                float xa[4];
                *(float4*)xa = xv;
                #pragma unroll
                for (int k = 0; k < 4; k++) {
                    float4 wav = *(const float4*)&was[c4 * 4 + k][iq * 4];
                    float4 wbv = *(const float4*)&wbs[c4 * 4 + k][iq * 4];
                    fma4(aq, xa[k], wav);
                    fma4(ak, xa[k], wbv);
                }
            }
            *(float4*)&qa[t][u][iq * 4] = aq;
            *(float4*)&kb[t][u][iq * 4] = ak;
        }
        __syncthreads();
        #pragma unroll
        for (int j = 0; j < 2; j++) {
            int w = tid + j * 256;
            if (w < 325) {
                int u = w / 13, v = (w % 13) * 2;
                #pragma unroll
                for (int t = 0; t < 2; t++) {
                    acc[j][0] += dot16v(qa[t][u], kb[t][v]);
                    if (v + 1 < V) acc[j][1] += dot16v(qa[t][u], kb[t][v + 1]);
                }
            }
        }
    }
    #pragma unroll
    for (int j = 0; j < 2; j++) {
        int w = tid + j * 256;
        if (w < 325) {
            int u = w / 13, v = (w % 13) * 2;
            size_t base = (size_t)(s * NN + n) * 625 + u * 25 + v;
            atomicAdd(&S1g[base], acc[j][0]);
            if (v + 1 < V) atomicAdd(&S1g[base + 1], acc[j][1]);
        }
    }
}

// ---------------------------------------------------------------------------
// k_a1: in place S1 row <- A_comb + w2 * softmax(S1row / 64)   (= ac1)
// ---------------------------------------------------------------------------
__global__ void k_a1(float* __restrict__ S1g, const float* __restrict__ A_comb,
                     const void* __restrict__ wA, const int* __restrict__ flagp) {
    int f32 = *flagp;
    float w2 = ldv(wA, 2, f32);
    int sn = blockIdx.x;
    int s = sn / NN;
    int u = threadIdx.x;
    if (u >= V) return;
    float* row = S1g + (size_t)sn * V * V + u * V;
    const float* ac = A_comb + (size_t)(s * V + u) * V;
    const float scale = 1.0f / 64.0f;
    float vals[V];
    float m = -1e30f;
    for (int v = 0; v < V; v++) { vals[v] = row[v] * scale; m = fmaxf(m, vals[v]); }
    float sum = 0.f;
    for (int v = 0; v < V; v++) { vals[v] = __expf(vals[v] - m); sum += vals[v]; }
    float inv = w2 / sum;
    for (int v = 0; v < V; v++) row[v] = ac[v] + vals[v] * inv;
}

// ---------------------------------------------------------------------------
// k_main: round-6 MFMA structure + prefetch-pipelined staging from wprep/ac1g.
//   A-frag: st[m][k], lane m=lane&15, koff=(lane>>4)*8 (short8)
//   B-frag: st[n][k], lane n=lane&15, same koff
//   C/D   : col=lane&15 (+16*nt), row=(lane>>4)*4+reg (+16*wave)
// ---------------------------------------------------------------------------
__global__ __launch_bounds__(256, 3) void k_main(
    const void* __restrict__ x,
    const void* __restrict__ ba, const void* __restrict__ bb,
    const void* __restrict__ bd,
    const void* __restrict__ gamma, const void* __restrict__ beta,
    const void* __restrict__ wA,
    const unsigned short* __restrict__ wprep,
    const float* __restrict__ ac1g,
    void* __restrict__ outp, const int* __restrict__ flagp) {
    int f32 = *flagp;
    int bx = blockIdx.x;
    int n = bx >> 7, tc = bx & 127;
    int t0 = tc * TB;
    int tid = threadIdx.x;
    int lane = tid & 63, wv = tid >> 6;
    int lm = lane & 15, kq = lane >> 4;

    __shared__ __align__(16) unsigned short xb[64 * 72];       // 9216 B
    __shared__ __align__(16) unsigned short wall[6912];        // 13824 B watb|wbtb|wdtb
    __shared__ __align__(16) unsigned short qab[64 * 40];      // 5120 B
    __shared__ __align__(16) unsigned short kbb[64 * 40];      // 5120 B
    __shared__ __align__(16) unsigned short Ainb[64 * 40];     // 5120 B
    __shared__ __align__(16) unsigned short xwtb[2 * 64 * 40]; // 10240 B
    __shared__ __align__(16) float ac1f[640];                  // 2560 B
    __shared__ float gs[O], bts[O], bds[O];                    // 768 B

    unsigned short* watb = wall;
    unsigned short* wbtb = wall + 1152;
    unsigned short* wdtb = wall + 2304;

    // ---- prefetch s=0 staging into registers (issued before x staging)
    uint4 rw[4];
    float ra[3];
    float rbq, rbk;
    {
        const uint4* p = (const uint4*)wprep;
        #pragma unroll
        for (int k = 0; k < 4; k++) {
            int j = tid + k * 256;
            if (j < 864) rw[k] = p[j];
        }
        const float* an = ac1g + (size_t)n * 625;
        #pragma unroll
        for (int k = 0; k < 3; k++) {
            int j = tid + k * 256;
            if (j < 625) ra[k] = an[j];
        }
        rbq = ldv(ba, lm, f32);
        rbk = ldv(bb, lm, f32);
    }

    // ---- stage xb (bf16, rows t*32+u, stride 72)
    if (f32) {
        const float4* xp = (const float4*)x + (size_t)(n * TT + t0) * 400;
        for (int w = tid; w < 800; w += 256) {
            int t = w / 400, r = w % 400, u = r >> 4, c4 = r & 15;
            float4 v = xp[w];
            unsigned short h[4] = {f2bf(v.x), f2bf(v.y), f2bf(v.z), f2bf(v.w)};
            *(uint2*)&xb[(t * 32 + u) * 72 + c4 * 4] = *(uint2*)h;
        }
    } else {
        const unsigned int* xp = (const unsigned int*)x;
        size_t base2 = (size_t)(n * TT + t0) * V * C / 2;
        for (int w = tid; w < 1600; w += 256) {
            int t = w / 800, r = w % 800, u = r >> 5, c2 = r & 31;
            ((unsigned int*)xb)[(t * 32 + u) * 36 + c2] = xp[base2 + (size_t)(t * V + u) * 32 + c2];
        }
    }
    // zero ghost rows u=25..31 (both t)
    for (int w = tid; w < 14 * 36; w += 256) {
        int idx = w / 36, word = w % 36;
        int row = (idx < 7) ? (25 + idx) : (32 + 25 + idx - 7);
        ((unsigned int*)xb)[row * 36 + word] = 0;
    }
    // zero col-pad words 32..35 of real rows
    for (int w = tid; w < 50 * 4; w += 256) {
        int idx = w >> 2, word = 32 + (w & 3);
        int row = (idx < 25) ? idx : (32 + idx - 25);
        ((unsigned int*)xb)[row * 36 + word] = 0;
    }
    // zero qab/kbb k-pad cols 16..31 once
    for (int w = tid; w < 512; w += 256) {
        int r = w >> 3, cw = 8 + (w & 7);
        ((unsigned int*)qab)[r * 20 + cw] = 0;
        ((unsigned int*)kbb)[r * 20 + cw] = 0;
    }
    if (tid < O) {
        bds[tid] = ldv(bd, tid, f32) + ldv(bd, O + tid, f32) + ldv(bd, 2 * O + tid, f32);
        gs[tid] = ldv(gamma, tid, f32) * rsqrtf(1.f + 1e-5f);
        bts[tid] = ldv(beta, tid, f32);
    }
    float w3 = ldv(wA, 3, f32);

    f32x4 acc[4];
    #pragma unroll
    for (int nt = 0; nt < 4; nt++) acc[nt] = (f32x4){0.f, 0.f, 0.f, 0.f};

    int t_ = wv >> 1;
    int mrow = wv * 16 + lm;
    int drow0 = wv * 16 + (kq << 2);
    int ub = ((wv & 1) << 4) + (kq << 2);

    for (int s = 0; s < S; s++) {
        // ---- write prefetched staging to LDS (wall/ac1f not read by P4)
        #pragma unroll
        for (int k = 0; k < 4; k++) {
            int j = tid + k * 256;
            if (j < 864) ((uint4*)wall)[j] = rw[k];
        }
        #pragma unroll
        for (int k = 0; k < 3; k++) {
            int j = tid + k * 256;
            if (j < 625) ac1f[j] = ra[k];
        }
        float bq_c = rbq, bk_c = rbk;
        __syncthreads();   // sync2

        // ---- prefetch s+1 (consumed at next loop top; hidden behind P1-P4)
        if (s < 2) {
            const uint4* p = (const uint4*)wprep + (size_t)(s + 1) * 864;
            #pragma unroll
            for (int k = 0; k < 4; k++) {
                int j = tid + k * 256;
                if (j < 864) rw[k] = p[j];
            }
            const float* an = ac1g + (size_t)((s + 1) * NN + n) * 625;
            #pragma unroll
            for (int k = 0; k < 3; k++) {
                int j = tid + k * 256;
                if (j < 625) ra[k] = an[j];
            }
            rbq = ldv(ba, (s + 1) * IC + lm, f32);
            rbk = ldv(bb, (s + 1) * IC + lm, f32);
        }

        // ---- P1: qa/kb MFMA
        short8 xa0 = *(const short8*)&xb[mrow * 72 + kq * 8];
        short8 xa1 = *(const short8*)&xb[mrow * 72 + 32 + kq * 8];
        {
            short8 wa0 = *(const short8*)&watb[lm * 72 + kq * 8];
            short8 wa1 = *(const short8*)&watb[lm * 72 + 32 + kq * 8];
            short8 wb0 = *(const short8*)&wbtb[lm * 72 + kq * 8];
            short8 wb1 = *(const short8*)&wbtb[lm * 72 + 32 + kq * 8];
            f32x4 q = __builtin_amdgcn_mfma_f32_16x16x32_bf16(xa0, wa0, (f32x4){0.f,0.f,0.f,0.f}, 0, 0, 0);
            q = __builtin_amdgcn_mfma_f32_16x16x32_bf16(xa1, wa1, q, 0, 0, 0);
            f32x4 k = __builtin_amdgcn_mfma_f32_16x16x32_bf16(xa0, wb0, (f32x4){0.f,0.f,0.f,0.f}, 0, 0, 0);
            k = __builtin_amdgcn_mfma_f32_16x16x32_bf16(xa1, wb1, k, 0, 0, 0);
            #pragma unroll
            for (int reg = 0; reg < 4; reg++) {
                qab[(drow0 + reg) * 40 + lm] = f2bf(q[reg] + bq_c);
                kbb[(drow0 + reg) * 40 + lm] = f2bf(k[reg] + bk_c);
            }
        }
        // ---- P3: xw = xb * Wd -> xwtb transposed [t][o][v]
        {
            #pragma unroll
            for (int nt = 0; nt < 4; nt++) {
                short8 wd0 = *(const short8*)&wdtb[(nt * 16 + lm) * 72 + kq * 8];
                short8 wd1 = *(const short8*)&wdtb[(nt * 16 + lm) * 72 + 32 + kq * 8];
                f32x4 xw = __builtin_amdgcn_mfma_f32_16x16x32_bf16(xa0, wd0, (f32x4){0.f,0.f,0.f,0.f}, 0, 0, 0);
                xw = __builtin_amdgcn_mfma_f32_16x16x32_bf16(xa1, wd1, xw, 0, 0, 0);
                unsigned short h[4] = {f2bf(xw[0]), f2bf(xw[1]), f2bf(xw[2]), f2bf(xw[3])};
                *(uint2*)&xwtb[t_ * 2560 + (nt * 16 + lm) * 40 + ub] = *(uint2*)h;
            }
        }
        __syncthreads();   // sync3

        // ---- P2: E MFMA -> exp -> rowsum(shfl) -> combine -> Ainb
        {
            short8 aq = *(const short8*)&qab[mrow * 40 + kq * 8];
            short8 bk0 = *(const short8*)&kbb[(t_ * 32 + lm) * 40 + kq * 8];
            short8 bk1 = *(const short8*)&kbb[(t_ * 32 + 16 + lm) * 40 + kq * 8];
            f32x4 e0 = __builtin_amdgcn_mfma_f32_16x16x32_bf16(aq, bk0, (f32x4){0.f,0.f,0.f,0.f}, 0, 0, 0);
            f32x4 e1 = __builtin_amdgcn_mfma_f32_16x16x32_bf16(aq, bk1, (f32x4){0.f,0.f,0.f,0.f}, 0, 0, 0);
            #pragma unroll
            for (int reg = 0; reg < 4; reg++) {
                float p0 = __expf(e0[reg] * 0.25f);
                float p1 = (lm < V - 16) ? __expf(e1[reg] * 0.25f) : 0.f;
                float pr = p0 + p1;
                pr += __shfl_xor(pr, 1);
                pr += __shfl_xor(pr, 2);
                pr += __shfl_xor(pr, 4);
                pr += __shfl_xor(pr, 8);
                float si = w3 / pr;
                int u = ub + reg;
                int uc = (u < V) ? u : 0;
                float a0v = (u < V) ? (ac1f[uc * 25 + lm] + si * p0) : 0.f;
                float a1v = (u < V && lm < V - 16) ? (ac1f[uc * 25 + 16 + lm] + si * p1) : 0.f;
                Ainb[(drow0 + reg) * 40 + lm] = f2bf(a0v);
                Ainb[(drow0 + reg) * 40 + 16 + lm] = f2bf(a1v);
            }
        }
        __syncthreads();   // sync4

        // ---- P4: y += Ainb * xwtb  (K=32, acc over s)
        {
            short8 aA = *(const short8*)&Ainb[mrow * 40 + kq * 8];
            #pragma unroll
            for (int nt = 0; nt < 4; nt++) {
                short8 bx8 = *(const short8*)&xwtb[t_ * 2560 + (nt * 16 + lm) * 40 + kq * 8];
                acc[nt] = __builtin_amdgcn_mfma_f32_16x16x32_bf16(aA, bx8, acc[nt], 0, 0, 0);
            }
        }
    }

    // ---- epilogue: BN + residual + relu
    #pragma unroll
    for (int nt = 0; nt < 4; nt++) {
        int o = nt * 16 + lm;
        float g = gs[o], bt_ = bts[o], bsum = bds[o];
        #pragma unroll
        for (int reg = 0; reg < 4; reg++) {
            int grow = drow0 + reg;
            int t = grow >> 5, u = grow & 31;
            if (u < V) {
                float xres = b2f(*(const bf16*)&xb[grow * 72 + o]);
                float yv = fmaxf((acc[nt][reg] + bsum) * g + bt_ + xres, 0.f);
                size_t ob = (size_t)((n * TT + t0 + t) * V + u) * O + o;
                if (f32) ((float*)outp)[ob] = yv;
                else     ((bf16*)outp)[ob] = __float2bfloat16(yv);
            }
        }
    }
}

// ---------------------------------------------------------------------------
extern "C" void kernel_launch(void* const* d_in, const int* in_sizes, int n_in,
                              void* d_out, int out_size, void* d_ws, size_t ws_size,
                              hipStream_t stream) {
    const void* x     = d_in[0];
    const void* A     = d_in[1];
    const void* PA    = d_in[2];
    const void* wA    = d_in[3];
    const void* Wa    = d_in[4];
    const void* ba    = d_in[5];
    const void* Wb    = d_in[6];
    const void* bb    = d_in[7];
    const void* Wd    = d_in[8];
    const void* bd    = d_in[9];
    const void* gamma = d_in[10];
    const void* beta  = d_in[11];

    int*   flagp  = (int*)d_ws;
    float* wsf    = (float*)d_ws;
    float* A_comb = wsf + 64;                         // 1875 f
    float* S1     = wsf + 2048;                       // 60000 f (becomes ac1)
    unsigned short* wprep = (unsigned short*)(wsf + 65536);  // 20736 sh

    k_detect<<<1, 64, 0, stream>>>(x, flagp);
    k_prep<<<64, 256, 0, stream>>>(A, PA, wA, Wa, Wb, Wd, A_comb, S1, wprep, flagp);
    k_s1<<<dim3(TT / TCH, NN, S), 256, 0, stream>>>(x, Wa, ba, Wb, bb, S1, flagp);
    k_a1<<<S * NN, 64, 0, stream>>>(S1, A_comb, wA, flagp);
    k_main<<<NN * TT / TB, 256, 0, stream>>>(x, ba, bb, bd, gamma, beta, wA,
                                             wprep, S1, d_out, flagp);
}

// Round 2
// 276.187 us; speedup vs baseline: 1.1351x; 1.1351x over previous
//
#include <hip/hip_runtime.h>
#include <hip/hip_bf16.h>

typedef __hip_bfloat16 bf16;
typedef __attribute__((ext_vector_type(8))) short short8;
typedef __attribute__((ext_vector_type(4))) float f32x4;

#define S  3
#define V  25
#define C  64
#define O  64
#define IC 16
#define NN 32
#define TT 256
#define TB 2
#define TCH 32

__device__ __forceinline__ float b2f(bf16 v) { return __bfloat162float(v); }

__device__ __forceinline__ float ldv(const void* p, size_t i, int f32) {
    return f32 ? ((const float*)p)[i] : b2f(((const bf16*)p)[i]);
}

__device__ __forceinline__ unsigned short f2bf(float f) {
    bf16 h = __float2bfloat16(f);
    return *(unsigned short*)&h;
}

__device__ __forceinline__ void fma4(float4& a, float s, float4 b) {
    a.x += s * b.x; a.y += s * b.y; a.z += s * b.z; a.w += s * b.w;
}

__device__ __forceinline__ float dot16v(const float* a, const float* b) {
    float4 a0 = *(const float4*)(a + 0),  a1 = *(const float4*)(a + 4);
    float4 a2 = *(const float4*)(a + 8),  a3 = *(const float4*)(a + 12);
    float4 b0 = *(const float4*)(b + 0),  b1 = *(const float4*)(b + 4);
    float4 b2 = *(const float4*)(b + 8),  b3 = *(const float4*)(b + 12);
    float e = a0.x*b0.x + a0.y*b0.y + a0.z*b0.z + a0.w*b0.w;
    e += a1.x*b1.x + a1.y*b1.y + a1.z*b1.z + a1.w*b1.w;
    e += a2.x*b2.x + a2.y*b2.y + a2.z*b2.z + a2.w*b2.w;
    e += a3.x*b3.x + a3.y*b3.y + a3.z*b3.z + a3.w*b3.w;
    return e;
}

// ---------------------------------------------------------------------------
// k_prep: integrated dtype sniff (per-block, wave-parallel; block 0 publishes
// the flag for the downstream kernels). Zero S1; convert weights to bf16
// transposed/padded MFMA layouts; compute A_comb.
// ---------------------------------------------------------------------------
__global__ __launch_bounds__(256) void k_prep(
    const void* __restrict__ x,
    const void* __restrict__ A, const void* __restrict__ PA,
    const void* __restrict__ wA,
    const void* __restrict__ Wa, const void* __restrict__ Wb,
    const void* __restrict__ Wd,
    float* __restrict__ A_comb, float* __restrict__ S1,
    unsigned short* __restrict__ wprep, int* __restrict__ flagp) {
    __shared__ int sflag;
    if (threadIdx.x < 64) {
        const bf16* p = (const bf16*)x;
        int bad = 0;
        #pragma unroll
        for (int k = 0; k < 32; k++) {
            float v = b2f(p[threadIdx.x + k * 64]);
            bad |= !(v > -1000.f && v < 1000.f);
        }
        unsigned long long m = __ballot(bad);
        if (threadIdx.x == 0) {
            sflag = (m != 0ull) ? 1 : 0;
            if (blockIdx.x == 0) *flagp = sflag;
        }
    }
    __syncthreads();
    int f32 = sflag;

    int g = blockIdx.x * 256 + threadIdx.x;
    int stride = gridDim.x * 256;

    for (int w = g; w < 60000; w += stride) S1[w] = 0.f;

    for (int w = g; w < 3456; w += stride) {           // Wa/Wb -> [i][c] bf16
        int s = w / 1152, r = w % 1152, i = r / 72, c = r % 72;
        unsigned short va = 0, vb = 0;
        if (c < 64) {
            va = f2bf(ldv(Wa, (size_t)s * 1024 + c * 16 + i, f32));
            vb = f2bf(ldv(Wb, (size_t)s * 1024 + c * 16 + i, f32));
        }
        wprep[s * 6912 + i * 72 + c] = va;
        wprep[s * 6912 + 1152 + i * 72 + c] = vb;
    }
    for (int w = g; w < 13824; w += stride) {          // Wd -> [o][c] bf16
        int s = w / 4608, r = w % 4608, o = r / 72, c = r % 72;
        unsigned short vd = 0;
        if (c < 64) vd = f2bf(ldv(Wd, (size_t)s * 4096 + c * 64 + o, f32));
        wprep[s * 6912 + 2304 + o * 72 + c] = vd;
    }

    if (g < S * V) {                                    // A_comb rows
        float w0 = ldv(wA, 0, f32), w1 = ldv(wA, 1, f32);
        float vals[V];
        float m = -1e30f;
        for (int v = 0; v < V; v++) { vals[v] = ldv(PA, g * V + v, f32); m = fmaxf(m, vals[v]); }
        float sum = 0.f;
        for (int v = 0; v < V; v++) { vals[v] = __expf(vals[v] - m); sum += vals[v]; }
        float inv = 1.f / sum;
        for (int v = 0; v < V; v++)
            A_comb[g * V + v] = w0 * ldv(A, g * V + v, f32) + w1 * vals[v] * inv;
    }
}

// ---------------------------------------------------------------------------
// k_s1: S1[s,n,u,v] = sum_t qa . kb   (unchanged, known-good)
// ---------------------------------------------------------------------------
__global__ __launch_bounds__(256) void k_s1(
    const void* __restrict__ x,
    const void* __restrict__ Wa, const void* __restrict__ ba,
    const void* __restrict__ Wb, const void* __restrict__ bb,
    float* __restrict__ S1g, const int* __restrict__ flagp) {
    int f32 = *flagp;
    int tchunk = blockIdx.x, n = blockIdx.y, s = blockIdx.z;
    int tid = threadIdx.x;

    __shared__ __align__(16) float xs[2][V][68];
    __shared__ __align__(16) float was[C][IC], wbs[C][IC];
    __shared__ __align__(16) float qa[2][V][20], kb[2][V][20];
    __shared__ __align__(16) float bas[IC], bbs[IC];

    if (f32) {
        const float4* Wa4 = (const float4*)Wa + s * 256;
        const float4* Wb4 = (const float4*)Wb + s * 256;
        if (tid < 256) { ((float4*)was)[tid] = Wa4[tid]; ((float4*)wbs)[tid] = Wb4[tid]; }
    } else {
        for (int w = tid; w < 1024; w += 256) {
            ((float*)was)[w] = ldv(Wa, (size_t)s * 1024 + w, 0);
            ((float*)wbs)[w] = ldv(Wb, (size_t)s * 1024 + w, 0);
        }
    }
    if (tid < IC) { bas[tid] = ldv(ba, s * IC + tid, f32); bbs[tid] = ldv(bb, s * IC + tid, f32); }

    float acc[2][2] = {{0.f, 0.f}, {0.f, 0.f}};
    int t0 = tchunk * TCH;
    for (int tt = 0; tt < TCH; tt += 2) {
        __syncthreads();
        if (f32) {
            const float4* xp = (const float4*)x + (size_t)(n * TT + t0 + tt) * 400;
            for (int w = tid; w < 800; w += 256) {
                int t = w / 400, r = w % 400;
                *(float4*)&xs[t][r >> 4][(r & 15) * 4] = xp[w];
            }
        } else {
            const uint2* xp = (const uint2*)x + (size_t)(n * TT + t0 + tt) * 400;
            for (int w = tid; w < 800; w += 256) {
                int t = w / 400, r = w % 400, u = r >> 4, c4 = r & 15;
                uint2 pk = xp[w];
                const bf16* h = (const bf16*)&pk;
                float4 f = {b2f(h[0]), b2f(h[1]), b2f(h[2]), b2f(h[3])};
                *(float4*)&xs[t][u][c4 * 4] = f;
            }
        }
        __syncthreads();
        if (tid < 200) {
            int u = tid >> 3, r = tid & 7, t = r >> 2, iq = r & 3;
            float4 aq = *(const float4*)&bas[iq * 4];
            float4 ak = *(const float4*)&bbs[iq * 4];
            #pragma unroll
            for (int c4 = 0; c4 < 16; c4++) {
                float4 xv = *(const float4*)&xs[t][u][c4 * 4];
                float xa[4];
                *(float4*)xa = xv;
                #pragma unroll
                for (int k = 0; k < 4; k++) {
                    float4 wav = *(const float4*)&was[c4 * 4 + k][iq * 4];
                    float4 wbv = *(const float4*)&wbs[c4 * 4 + k][iq * 4];
                    fma4(aq, xa[k], wav);
                    fma4(ak, xa[k], wbv);
                }
            }
            *(float4*)&qa[t][u][iq * 4] = aq;
            *(float4*)&kb[t][u][iq * 4] = ak;
        }
        __syncthreads();
        #pragma unroll
        for (int j = 0; j < 2; j++) {
            int w = tid + j * 256;
            if (w < 325) {
                int u = w / 13, v = (w % 13) * 2;
                #pragma unroll
                for (int t = 0; t < 2; t++) {
                    acc[j][0] += dot16v(qa[t][u], kb[t][v]);
                    if (v + 1 < V) acc[j][1] += dot16v(qa[t][u], kb[t][v + 1]);
                }
            }
        }
    }
    #pragma unroll
    for (int j = 0; j < 2; j++) {
        int w = tid + j * 256;
        if (w < 325) {
            int u = w / 13, v = (w % 13) * 2;
            size_t base = (size_t)(s * NN + n) * 625 + u * 25 + v;
            atomicAdd(&S1g[base], acc[j][0]);
            if (v + 1 < V) atomicAdd(&S1g[base + 1], acc[j][1]);
        }
    }
}

// ---------------------------------------------------------------------------
// k_a1: in place S1 row <- A_comb + w2 * softmax(S1row / 64)   (= ac1)
// ---------------------------------------------------------------------------
__global__ void k_a1(float* __restrict__ S1g, const float* __restrict__ A_comb,
                     const void* __restrict__ wA, const int* __restrict__ flagp) {
    int f32 = *flagp;
    float w2 = ldv(wA, 2, f32);
    int sn = blockIdx.x;
    int s = sn / NN;
    int u = threadIdx.x;
    if (u >= V) return;
    float* row = S1g + (size_t)sn * V * V + u * V;
    const float* ac = A_comb + (size_t)(s * V + u) * V;
    const float scale = 1.0f / 64.0f;
    float vals[V];
    float m = -1e30f;
    for (int v = 0; v < V; v++) { vals[v] = row[v] * scale; m = fmaxf(m, vals[v]); }
    float sum = 0.f;
    for (int v = 0; v < V; v++) { vals[v] = __expf(vals[v] - m); sum += vals[v]; }
    float inv = w2 / sum;
    for (int v = 0; v < V; v++) row[v] = ac[v] + vals[v] * inv;
}

// ---------------------------------------------------------------------------
// k_main round-2 restructure:
//   - wall/ac1f LDS staging REMOVED: weight fragments + ac1 rows are L2-hot
//     (41KB wprep / 7.5KB ac1 shared by all 4096 blocks) -> direct global
//     loads. LDS 52224 -> 30464 B => 5 blocks/CU (was 3).
//   - Ainb folded in-place into qab (all qab row traffic is wave-private;
//     within-wave LDS ordering makes read-then-write safe). P4 re-zeros
//     qab cols 16..31 (the K-pad the next P2's aq read needs).
//   - 2 barriers per s-iter (was 3): only kbb (P1->P2) and xwtb (P3->P4 and
//     cross-iter overwrite) are cross-wave.
//   - epilogue: block output is one contiguous 6400B region -> stage bf16
//     results in xwtb and dump coalesced uint4 (kills 4.7x write amplif.).
// ---------------------------------------------------------------------------
__global__ __launch_bounds__(256, 5) void k_main(
    const void* __restrict__ x,
    const void* __restrict__ ba, const void* __restrict__ bb,
    const void* __restrict__ bd,
    const void* __restrict__ gamma, const void* __restrict__ beta,
    const void* __restrict__ wA,
    const unsigned short* __restrict__ wprep,
    const float* __restrict__ ac1g,
    void* __restrict__ outp, const int* __restrict__ flagp) {
    int f32 = *flagp;
    int bx = blockIdx.x;
    int n = bx >> 7, tc = bx & 127;
    int t0 = tc * TB;
    int tid = threadIdx.x;
    int lane = tid & 63, wv = tid >> 6;
    int lm = lane & 15, kq = lane >> 4;

    __shared__ __align__(16) unsigned short xb[64 * 72];       // 9216 B
    __shared__ __align__(16) unsigned short qab[64 * 40];      // 5120 B (q | later A_in)
    __shared__ __align__(16) unsigned short kbb[64 * 40];      // 5120 B
    __shared__ __align__(16) unsigned short xwtb[2 * 64 * 40]; // 10240 B (later epilogue stage)
    __shared__ float gs[O], bts[O], bds[O];                    // 768 B
    // total 30464 B -> 5 blocks/CU

    // ---- stage xb (bf16, rows t*32+u, stride 72)
    if (f32) {
        const float4* xp = (const float4*)x + (size_t)(n * TT + t0) * 400;
        for (int w = tid; w < 800; w += 256) {
            int t = w / 400, r = w % 400, u = r >> 4, c4 = r & 15;
            float4 v = xp[w];
            unsigned short h[4] = {f2bf(v.x), f2bf(v.y), f2bf(v.z), f2bf(v.w)};
            *(uint2*)&xb[(t * 32 + u) * 72 + c4 * 4] = *(uint2*)h;
        }
    } else {
        const unsigned int* xp = (const unsigned int*)x;
        size_t base2 = (size_t)(n * TT + t0) * V * C / 2;
        for (int w = tid; w < 1600; w += 256) {
            int t = w / 800, r = w % 800, u = r >> 5, c2 = r & 31;
            ((unsigned int*)xb)[(t * 32 + u) * 36 + c2] = xp[base2 + (size_t)(t * V + u) * 32 + c2];
        }
    }
    // zero ghost rows u=25..31 (both t)
    for (int w = tid; w < 14 * 36; w += 256) {
        int idx = w / 36, word = w % 36;
        int row = (idx < 7) ? (25 + idx) : (32 + 25 + idx - 7);
        ((unsigned int*)xb)[row * 36 + word] = 0;
    }
    // zero col-pad words 32..35 of real rows
    for (int w = tid; w < 50 * 4; w += 256) {
        int idx = w >> 2, word = 32 + (w & 3);
        int row = (idx < 25) ? idx : (32 + idx - 25);
        ((unsigned int*)xb)[row * 36 + word] = 0;
    }
    // zero qab/kbb k-pad cols 16..31 (kbb: permanent; qab: refreshed by P4)
    for (int w = tid; w < 512; w += 256) {
        int r = w >> 3, cw = 8 + (w & 7);
        ((unsigned int*)qab)[r * 20 + cw] = 0;
        ((unsigned int*)kbb)[r * 20 + cw] = 0;
    }
    if (tid < O) {
        bds[tid] = ldv(bd, tid, f32) + ldv(bd, O + tid, f32) + ldv(bd, 2 * O + tid, f32);
        gs[tid] = ldv(gamma, tid, f32) * rsqrtf(1.f + 1e-5f);
        bts[tid] = ldv(beta, tid, f32);
    }
    float w3 = ldv(wA, 3, f32);

    f32x4 acc[4];
    #pragma unroll
    for (int nt = 0; nt < 4; nt++) acc[nt] = (f32x4){0.f, 0.f, 0.f, 0.f};

    int t_ = wv >> 1;
    int mrow = wv * 16 + lm;
    int drow0 = wv * 16 + (kq << 2);
    int ub = ((wv & 1) << 4) + (kq << 2);

    __syncthreads();   // xb / pads / gs ready

    // x fragments are loop-invariant: hoist
    short8 xa0 = *(const short8*)&xb[mrow * 72 + kq * 8];
    short8 xa1 = *(const short8*)&xb[mrow * 72 + 32 + kq * 8];

    for (int s = 0; s < S; s++) {
        const unsigned short* watg = wprep + s * 6912;
        const unsigned short* wbtg = watg + 1152;
        const unsigned short* wdtg = watg + 2304;
        const float* acn = ac1g + ((size_t)s * NN + n) * 625;

        // ---- P1: qa/kb MFMA (weights direct from L2-hot global)
        {
            short8 wa0 = *(const short8*)&watg[lm * 72 + kq * 8];
            short8 wa1 = *(const short8*)&watg[lm * 72 + 32 + kq * 8];
            short8 wb0 = *(const short8*)&wbtg[lm * 72 + kq * 8];
            short8 wb1 = *(const short8*)&wbtg[lm * 72 + 32 + kq * 8];
            float bq_c = ldv(ba, s * IC + lm, f32);
            float bk_c = ldv(bb, s * IC + lm, f32);
            f32x4 q = __builtin_amdgcn_mfma_f32_16x16x32_bf16(xa0, wa0, (f32x4){0.f,0.f,0.f,0.f}, 0, 0, 0);
            q = __builtin_amdgcn_mfma_f32_16x16x32_bf16(xa1, wa1, q, 0, 0, 0);
            f32x4 k = __builtin_amdgcn_mfma_f32_16x16x32_bf16(xa0, wb0, (f32x4){0.f,0.f,0.f,0.f}, 0, 0, 0);
            k = __builtin_amdgcn_mfma_f32_16x16x32_bf16(xa1, wb1, k, 0, 0, 0);
            #pragma unroll
            for (int reg = 0; reg < 4; reg++) {
                qab[(drow0 + reg) * 40 + lm] = f2bf(q[reg] + bq_c);
                kbb[(drow0 + reg) * 40 + lm] = f2bf(k[reg] + bk_c);
            }
        }
        // ---- P3: xw = xb * Wd -> xwtb transposed [t][o][v]
        {
            #pragma unroll
            for (int nt = 0; nt < 4; nt++) {
                short8 wd0 = *(const short8*)&wdtg[(nt * 16 + lm) * 72 + kq * 8];
                short8 wd1 = *(const short8*)&wdtg[(nt * 16 + lm) * 72 + 32 + kq * 8];
                f32x4 xw = __builtin_amdgcn_mfma_f32_16x16x32_bf16(xa0, wd0, (f32x4){0.f,0.f,0.f,0.f}, 0, 0, 0);
                xw = __builtin_amdgcn_mfma_f32_16x16x32_bf16(xa1, wd1, xw, 0, 0, 0);
                unsigned short h[4] = {f2bf(xw[0]), f2bf(xw[1]), f2bf(xw[2]), f2bf(xw[3])};
                *(uint2*)&xwtb[t_ * 2560 + (nt * 16 + lm) * 40 + ub] = *(uint2*)h;
            }
        }
        __syncthreads();   // sync_A: kbb (P1->P2, cross-wave), xwtb (P3->P4, cross-wave)

        // ---- P2: E MFMA -> exp -> rowsum(shfl) -> combine -> A_in (into qab, in place)
        {
            short8 aq = *(const short8*)&qab[mrow * 40 + kq * 8];
            short8 bk0 = *(const short8*)&kbb[(t_ * 32 + lm) * 40 + kq * 8];
            short8 bk1 = *(const short8*)&kbb[(t_ * 32 + 16 + lm) * 40 + kq * 8];
            f32x4 e0 = __builtin_amdgcn_mfma_f32_16x16x32_bf16(aq, bk0, (f32x4){0.f,0.f,0.f,0.f}, 0, 0, 0);
            f32x4 e1 = __builtin_amdgcn_mfma_f32_16x16x32_bf16(aq, bk1, (f32x4){0.f,0.f,0.f,0.f}, 0, 0, 0);
            #pragma unroll
            for (int reg = 0; reg < 4; reg++) {
                float p0 = __expf(e0[reg] * 0.25f);
                float p1 = (lm < V - 16) ? __expf(e1[reg] * 0.25f) : 0.f;
                float pr = p0 + p1;
                pr += __shfl_xor(pr, 1);
                pr += __shfl_xor(pr, 2);
                pr += __shfl_xor(pr, 4);
                pr += __shfl_xor(pr, 8);
                float si = w3 / pr;
                int u = ub + reg;
                int uc = (u < V) ? u : 0;
                float a0v = (u < V) ? (acn[uc * 25 + lm] + si * p0) : 0.f;
                float a1v = (u < V && lm < V - 16) ? (acn[uc * 25 + 16 + lm] + si * p1) : 0.f;
                qab[(drow0 + reg) * 40 + lm] = f2bf(a0v);
                qab[(drow0 + reg) * 40 + 16 + lm] = f2bf(a1v);
            }
        }
        // ---- P4: y += A_in * xwtb  (no barrier needed: qab rows wave-private,
        //      xwtb written pre-sync_A)
        {
            short8 aA = *(const short8*)&qab[mrow * 40 + kq * 8];
            #pragma unroll
            for (int nt = 0; nt < 4; nt++) {
                short8 bx8 = *(const short8*)&xwtb[t_ * 2560 + (nt * 16 + lm) * 40 + kq * 8];
                acc[nt] = __builtin_amdgcn_mfma_f32_16x16x32_bf16(aA, bx8, acc[nt], 0, 0, 0);
            }
            // restore qab K-pad zeros for next s's aq read (wave-private rows)
            if (s < S - 1) {
                #pragma unroll
                for (int reg = 0; reg < 4; reg++)
                    qab[(drow0 + reg) * 40 + 16 + lm] = 0;
            }
        }
        __syncthreads();   // sync_B: next-iter P1/P3 overwrite kbb/xwtb
    }

    // ---- epilogue: BN + residual + relu
    if (f32) {
        #pragma unroll
        for (int nt = 0; nt < 4; nt++) {
            int o = nt * 16 + lm;
            float g = gs[o], bt_ = bts[o], bsum = bds[o];
            #pragma unroll
            for (int reg = 0; reg < 4; reg++) {
                int grow = drow0 + reg;
                int t = grow >> 5, u = grow & 31;
                if (u < V) {
                    float xres = b2f(*(const bf16*)&xb[grow * 72 + o]);
                    float yv = fmaxf((acc[nt][reg] + bsum) * g + bt_ + xres, 0.f);
                    size_t ob = (size_t)((n * TT + t0 + t) * V + u) * O + o;
                    ((float*)outp)[ob] = yv;
                }
            }
        }
    } else {
        // stage bf16 results in xwtb (free after last P4 + sync_B), then dump
        // the block's contiguous 6400B output with coalesced 16B stores.
        unsigned short* ep = xwtb;
        #pragma unroll
        for (int nt = 0; nt < 4; nt++) {
            int o = nt * 16 + lm;
            float g = gs[o], bt_ = bts[o], bsum = bds[o];
            #pragma unroll
            for (int reg = 0; reg < 4; reg++) {
                int grow = drow0 + reg;
                int t = grow >> 5, u = grow & 31;
                if (u < V) {
                    float xres = b2f(*(const bf16*)&xb[grow * 72 + o]);
                    float yv = fmaxf((acc[nt][reg] + bsum) * g + bt_ + xres, 0.f);
                    ep[(t * V + u) * O + o] = f2bf(yv);
                }
            }
        }
        __syncthreads();
        uint4* outv = (uint4*)((bf16*)outp + (size_t)(n * TT + t0) * V * O);
        const uint4* epv = (const uint4*)ep;
        for (int w = tid; w < 400; w += 256) outv[w] = epv[w];
    }
}

// ---------------------------------------------------------------------------
extern "C" void kernel_launch(void* const* d_in, const int* in_sizes, int n_in,
                              void* d_out, int out_size, void* d_ws, size_t ws_size,
                              hipStream_t stream) {
    const void* x     = d_in[0];
    const void* A     = d_in[1];
    const void* PA    = d_in[2];
    const void* wA    = d_in[3];
    const void* Wa    = d_in[4];
    const void* ba    = d_in[5];
    const void* Wb    = d_in[6];
    const void* bb    = d_in[7];
    const void* Wd    = d_in[8];
    const void* bd    = d_in[9];
    const void* gamma = d_in[10];
    const void* beta  = d_in[11];

    int*   flagp  = (int*)d_ws;
    float* wsf    = (float*)d_ws;
    float* A_comb = wsf + 64;                         // 1875 f
    float* S1     = wsf + 2048;                       // 60000 f (becomes ac1)
    unsigned short* wprep = (unsigned short*)(wsf + 65536);  // 20736 sh

    k_prep<<<64, 256, 0, stream>>>(x, A, PA, wA, Wa, Wb, Wd, A_comb, S1, wprep, flagp);
    k_s1<<<dim3(TT / TCH, NN, S), 256, 0, stream>>>(x, Wa, ba, Wb, bb, S1, flagp);
    k_a1<<<S * NN, 64, 0, stream>>>(S1, A_comb, wA, flagp);
    k_main<<<NN * TT / TB, 256, 0, stream>>>(x, ba, bb, bd, gamma, beta, wA,
                                             wprep, S1, d_out, flagp);
}

// Round 3
// 212.611 us; speedup vs baseline: 1.4746x; 1.2990x over previous
//
#include <hip/hip_runtime.h>
#include <hip/hip_bf16.h>

typedef __hip_bfloat16 bf16;
typedef __attribute__((ext_vector_type(8))) short short8;
typedef __attribute__((ext_vector_type(4))) float f32x4;

#define S  3
#define V  25
#define C  64
#define O  64
#define IC 16
#define NN 32
#define TT 256
#define TB 2
#define TCH 16

__device__ __forceinline__ float b2f(bf16 v) { return __bfloat162float(v); }

__device__ __forceinline__ float ldv(const void* p, size_t i, int f32) {
    return f32 ? ((const float*)p)[i] : b2f(((const bf16*)p)[i]);
}

__device__ __forceinline__ unsigned short f2bf(float f) {
    bf16 h = __float2bfloat16(f);
    return *(unsigned short*)&h;
}

// ---------------------------------------------------------------------------
// k_prep: integrated dtype sniff (per-block, wave-parallel; block 0 publishes
// the flag for the downstream kernels). Zero S1; convert weights to bf16
// transposed/padded MFMA layouts; compute A_comb.
// ---------------------------------------------------------------------------
__global__ __launch_bounds__(256) void k_prep(
    const void* __restrict__ x,
    const void* __restrict__ A, const void* __restrict__ PA,
    const void* __restrict__ wA,
    const void* __restrict__ Wa, const void* __restrict__ Wb,
    const void* __restrict__ Wd,
    float* __restrict__ A_comb, float* __restrict__ S1,
    unsigned short* __restrict__ wprep, int* __restrict__ flagp) {
    __shared__ int sflag;
    if (threadIdx.x < 64) {
        const bf16* p = (const bf16*)x;
        int bad = 0;
        #pragma unroll
        for (int k = 0; k < 32; k++) {
            float v = b2f(p[threadIdx.x + k * 64]);
            bad |= !(v > -1000.f && v < 1000.f);
        }
        unsigned long long m = __ballot(bad);
        if (threadIdx.x == 0) {
            sflag = (m != 0ull) ? 1 : 0;
            if (blockIdx.x == 0) *flagp = sflag;
        }
    }
    __syncthreads();
    int f32 = sflag;

    int g = blockIdx.x * 256 + threadIdx.x;
    int stride = gridDim.x * 256;

    for (int w = g; w < 60000; w += stride) S1[w] = 0.f;

    for (int w = g; w < 3456; w += stride) {           // Wa/Wb -> [i][c] bf16
        int s = w / 1152, r = w % 1152, i = r / 72, c = r % 72;
        unsigned short va = 0, vb = 0;
        if (c < 64) {
            va = f2bf(ldv(Wa, (size_t)s * 1024 + c * 16 + i, f32));
            vb = f2bf(ldv(Wb, (size_t)s * 1024 + c * 16 + i, f32));
        }
        wprep[s * 6912 + i * 72 + c] = va;
        wprep[s * 6912 + 1152 + i * 72 + c] = vb;
    }
    for (int w = g; w < 13824; w += stride) {          // Wd -> [o][c] bf16
        int s = w / 4608, r = w % 4608, o = r / 72, c = r % 72;
        unsigned short vd = 0;
        if (c < 64) vd = f2bf(ldv(Wd, (size_t)s * 4096 + c * 64 + o, f32));
        wprep[s * 6912 + 2304 + o * 72 + c] = vd;
    }

    if (g < S * V) {                                    // A_comb rows
        float w0 = ldv(wA, 0, f32), w1 = ldv(wA, 1, f32);
        float vals[V];
        float m = -1e30f;
        for (int v = 0; v < V; v++) { vals[v] = ldv(PA, g * V + v, f32); m = fmaxf(m, vals[v]); }
        float sum = 0.f;
        for (int v = 0; v < V; v++) { vals[v] = __expf(vals[v] - m); sum += vals[v]; }
        float inv = 1.f / sum;
        for (int v = 0; v < V; v++)
            A_comb[g * V + v] = w0 * ldv(A, g * V + v, f32) + w1 * vals[v] * inv;
    }
}

// ---------------------------------------------------------------------------
// k_s1 round-3 rewrite: MFMA instead of VALU dot-products (was MfmaUtil=0,
// VALUBusy 38%, 109us).
//   Per block = (tchunk of 16 t, n, s). Loop over t-pairs:
//     P1 (same fragment pattern as k_main): qa/kb = xb * Wa/Wb -> LDS
//     E: one 16x16x32 MFMA per wave; K=32 packs BOTH timesteps
//        (k<16 -> t0, k>=16 -> t1), so E accumulates sum_t qa.kb directly.
//   Each wave owns one 16x16 quadrant of the 25x25 S1 tile; ghost rows
//   (u,v>=25) are computed but never stored. atomicAdd at end (8 tchunk
//   blocks reduce into the same (s,n) tile).
// ---------------------------------------------------------------------------
__global__ __launch_bounds__(256) void k_s1(
    const void* __restrict__ x,
    const unsigned short* __restrict__ wprep,
    const void* __restrict__ ba, const void* __restrict__ bb,
    float* __restrict__ S1g, const int* __restrict__ flagp) {
    int f32 = *flagp;
    int tchunk = blockIdx.x, n = blockIdx.y, s = blockIdx.z;
    int tid = threadIdx.x;
    int lane = tid & 63, wv = tid >> 6;
    int lm = lane & 15, kq = lane >> 4;

    __shared__ __align__(16) unsigned short xb[64 * 72];   // 9216 B
    __shared__ __align__(16) unsigned short wqk[2304];     // 4608 B  wat|wbt
    __shared__ __align__(16) unsigned short qab[64 * 20];  // 2560 B
    __shared__ __align__(16) unsigned short kbb[64 * 20];  // 2560 B

    // stage weights once (wprep layout from k_prep: per s [wat 16x72 | wbt 16x72 | ...])
    {
        const uint4* p = (const uint4*)(wprep + (size_t)s * 6912);
        for (int w = tid; w < 288; w += 256) ((uint4*)wqk)[w] = p[w];
    }
    float bq_c = ldv(ba, s * IC + lm, f32);
    float bk_c = ldv(bb, s * IC + lm, f32);

    int mrow = wv * 16 + lm;
    int drow0 = wv * 16 + (kq << 2);
    int ur0 = ((wv >> 1) & 1) << 4;   // wave quadrant: rows
    int vc0 = (wv & 1) << 4;          //                cols
    int t0 = tchunk * TCH;
    int tsel = (kq >> 1) << 5;        // E-frag: k<16 -> t0 rows, k>=16 -> t1 rows
    int ksel = (kq & 1) << 3;

    f32x4 acc = {0.f, 0.f, 0.f, 0.f};

    for (int tt = 0; tt < TCH; tt += 2) {
        // ---- stage xb for timesteps (t0+tt, t0+tt+1); overlap E of prev pair
        if (f32) {
            const float4* xp = (const float4*)x + (size_t)(n * TT + t0 + tt) * 400;
            for (int w = tid; w < 800; w += 256) {
                int t = w / 400, r = w % 400, u = r >> 4, c4 = r & 15;
                float4 v = xp[w];
                unsigned short h[4] = {f2bf(v.x), f2bf(v.y), f2bf(v.z), f2bf(v.w)};
                *(uint2*)&xb[(t * 32 + u) * 72 + c4 * 4] = *(uint2*)h;
            }
        } else {
            const unsigned int* xp = (const unsigned int*)x;
            size_t base2 = (size_t)(n * TT + t0 + tt) * V * C / 2;
            for (int w = tid; w < 1600; w += 256) {
                int t = w / 800, r = w % 800, u = r >> 5, c2 = r & 31;
                ((unsigned int*)xb)[(t * 32 + u) * 36 + c2] = xp[base2 + (size_t)(t * V + u) * 32 + c2];
            }
        }
        if (tt > 0) {   // E for previous pair (reads qab/kbb, not xb)
            short8 a = *(const short8*)&qab[(tsel + ur0 + lm) * 20 + ksel];
            short8 b = *(const short8*)&kbb[(tsel + vc0 + lm) * 20 + ksel];
            acc = __builtin_amdgcn_mfma_f32_16x16x32_bf16(a, b, acc, 0, 0, 0);
        }
        __syncthreads();   // xb ready; prev E done before qab overwrite

        // ---- P1: qa/kb MFMA (identical fragment pattern to k_main)
        {
            short8 xa0 = *(const short8*)&xb[mrow * 72 + kq * 8];
            short8 xa1 = *(const short8*)&xb[mrow * 72 + 32 + kq * 8];
            short8 wa0 = *(const short8*)&wqk[lm * 72 + kq * 8];
            short8 wa1 = *(const short8*)&wqk[lm * 72 + 32 + kq * 8];
            short8 wb0 = *(const short8*)&wqk[1152 + lm * 72 + kq * 8];
            short8 wb1 = *(const short8*)&wqk[1152 + lm * 72 + 32 + kq * 8];
            f32x4 q = __builtin_amdgcn_mfma_f32_16x16x32_bf16(xa0, wa0, (f32x4){0.f,0.f,0.f,0.f}, 0, 0, 0);
            q = __builtin_amdgcn_mfma_f32_16x16x32_bf16(xa1, wa1, q, 0, 0, 0);
            f32x4 k = __builtin_amdgcn_mfma_f32_16x16x32_bf16(xa0, wb0, (f32x4){0.f,0.f,0.f,0.f}, 0, 0, 0);
            k = __builtin_amdgcn_mfma_f32_16x16x32_bf16(xa1, wb1, k, 0, 0, 0);
            #pragma unroll
            for (int reg = 0; reg < 4; reg++) {
                qab[(drow0 + reg) * 20 + lm] = f2bf(q[reg] + bq_c);
                kbb[(drow0 + reg) * 20 + lm] = f2bf(k[reg] + bk_c);
            }
        }
        __syncthreads();   // qab/kbb ready for E
    }
    // ---- final E for last pair
    {
        short8 a = *(const short8*)&qab[(tsel + ur0 + lm) * 20 + ksel];
        short8 b = *(const short8*)&kbb[(tsel + vc0 + lm) * 20 + ksel];
        acc = __builtin_amdgcn_mfma_f32_16x16x32_bf16(a, b, acc, 0, 0, 0);
    }

    // ---- reduce into S1 (C-layout: row = kq*4+reg, col = lm)
    float* dst = S1g + (size_t)(s * NN + n) * 625;
    #pragma unroll
    for (int reg = 0; reg < 4; reg++) {
        int u = ur0 + (kq << 2) + reg, v = vc0 + lm;
        if (u < V && v < V) atomicAdd(&dst[u * 25 + v], acc[reg]);
    }
}

// ---------------------------------------------------------------------------
// k_a1: in place S1 row <- A_comb + w2 * softmax(S1row / 64)   (= ac1)
// ---------------------------------------------------------------------------
__global__ void k_a1(float* __restrict__ S1g, const float* __restrict__ A_comb,
                     const void* __restrict__ wA, const int* __restrict__ flagp) {
    int f32 = *flagp;
    float w2 = ldv(wA, 2, f32);
    int sn = blockIdx.x;
    int s = sn / NN;
    int u = threadIdx.x;
    if (u >= V) return;
    float* row = S1g + (size_t)sn * V * V + u * V;
    const float* ac = A_comb + (size_t)(s * V + u) * V;
    const float scale = 1.0f / 64.0f;
    float vals[V];
    float m = -1e30f;
    for (int v = 0; v < V; v++) { vals[v] = row[v] * scale; m = fmaxf(m, vals[v]); }
    float sum = 0.f;
    for (int v = 0; v < V; v++) { vals[v] = __expf(vals[v] - m); sum += vals[v]; }
    float inv = w2 / sum;
    for (int v = 0; v < V; v++) row[v] = ac[v] + vals[v] * inv;
}

// ---------------------------------------------------------------------------
// k_main (round-2 structure, unchanged): direct-global weight fragments,
// in-place qab/A_in, 2 barriers per s-iter, coalesced staged epilogue.
// ---------------------------------------------------------------------------
__global__ __launch_bounds__(256, 5) void k_main(
    const void* __restrict__ x,
    const void* __restrict__ ba, const void* __restrict__ bb,
    const void* __restrict__ bd,
    const void* __restrict__ gamma, const void* __restrict__ beta,
    const void* __restrict__ wA,
    const unsigned short* __restrict__ wprep,
    const float* __restrict__ ac1g,
    void* __restrict__ outp, const int* __restrict__ flagp) {
    int f32 = *flagp;
    int bx = blockIdx.x;
    int n = bx >> 7, tc = bx & 127;
    int t0 = tc * TB;
    int tid = threadIdx.x;
    int lane = tid & 63, wv = tid >> 6;
    int lm = lane & 15, kq = lane >> 4;

    __shared__ __align__(16) unsigned short xb[64 * 72];       // 9216 B
    __shared__ __align__(16) unsigned short qab[64 * 40];      // 5120 B (q | later A_in)
    __shared__ __align__(16) unsigned short kbb[64 * 40];      // 5120 B
    __shared__ __align__(16) unsigned short xwtb[2 * 64 * 40]; // 10240 B (later epilogue stage)
    __shared__ float gs[O], bts[O], bds[O];                    // 768 B

    // ---- stage xb (bf16, rows t*32+u, stride 72)
    if (f32) {
        const float4* xp = (const float4*)x + (size_t)(n * TT + t0) * 400;
        for (int w = tid; w < 800; w += 256) {
            int t = w / 400, r = w % 400, u = r >> 4, c4 = r & 15;
            float4 v = xp[w];
            unsigned short h[4] = {f2bf(v.x), f2bf(v.y), f2bf(v.z), f2bf(v.w)};
            *(uint2*)&xb[(t * 32 + u) * 72 + c4 * 4] = *(uint2*)h;
        }
    } else {
        const unsigned int* xp = (const unsigned int*)x;
        size_t base2 = (size_t)(n * TT + t0) * V * C / 2;
        for (int w = tid; w < 1600; w += 256) {
            int t = w / 800, r = w % 800, u = r >> 5, c2 = r & 31;
            ((unsigned int*)xb)[(t * 32 + u) * 36 + c2] = xp[base2 + (size_t)(t * V + u) * 32 + c2];
        }
    }
    // zero ghost rows u=25..31 (both t)
    for (int w = tid; w < 14 * 36; w += 256) {
        int idx = w / 36, word = w % 36;
        int row = (idx < 7) ? (25 + idx) : (32 + 25 + idx - 7);
        ((unsigned int*)xb)[row * 36 + word] = 0;
    }
    // zero col-pad words 32..35 of real rows
    for (int w = tid; w < 50 * 4; w += 256) {
        int idx = w >> 2, word = 32 + (w & 3);
        int row = (idx < 25) ? idx : (32 + idx - 25);
        ((unsigned int*)xb)[row * 36 + word] = 0;
    }
    // zero qab/kbb k-pad cols 16..31 (kbb: permanent; qab: refreshed by P4)
    for (int w = tid; w < 512; w += 256) {
        int r = w >> 3, cw = 8 + (w & 7);
        ((unsigned int*)qab)[r * 20 + cw] = 0;
        ((unsigned int*)kbb)[r * 20 + cw] = 0;
    }
    if (tid < O) {
        bds[tid] = ldv(bd, tid, f32) + ldv(bd, O + tid, f32) + ldv(bd, 2 * O + tid, f32);
        gs[tid] = ldv(gamma, tid, f32) * rsqrtf(1.f + 1e-5f);
        bts[tid] = ldv(beta, tid, f32);
    }
    float w3 = ldv(wA, 3, f32);

    f32x4 acc[4];
    #pragma unroll
    for (int nt = 0; nt < 4; nt++) acc[nt] = (f32x4){0.f, 0.f, 0.f, 0.f};

    int t_ = wv >> 1;
    int mrow = wv * 16 + lm;
    int drow0 = wv * 16 + (kq << 2);
    int ub = ((wv & 1) << 4) + (kq << 2);

    __syncthreads();   // xb / pads / gs ready

    // x fragments are loop-invariant: hoist
    short8 xa0 = *(const short8*)&xb[mrow * 72 + kq * 8];
    short8 xa1 = *(const short8*)&xb[mrow * 72 + 32 + kq * 8];

    for (int s = 0; s < S; s++) {
        const unsigned short* watg = wprep + s * 6912;
        const unsigned short* wbtg = watg + 1152;
        const unsigned short* wdtg = watg + 2304;
        const float* acn = ac1g + ((size_t)s * NN + n) * 625;

        // ---- P1: qa/kb MFMA (weights direct from L2-hot global)
        {
            short8 wa0 = *(const short8*)&watg[lm * 72 + kq * 8];
            short8 wa1 = *(const short8*)&watg[lm * 72 + 32 + kq * 8];
            short8 wb0 = *(const short8*)&wbtg[lm * 72 + kq * 8];
            short8 wb1 = *(const short8*)&wbtg[lm * 72 + 32 + kq * 8];
            float bq_c = ldv(ba, s * IC + lm, f32);
            float bk_c = ldv(bb, s * IC + lm, f32);
            f32x4 q = __builtin_amdgcn_mfma_f32_16x16x32_bf16(xa0, wa0, (f32x4){0.f,0.f,0.f,0.f}, 0, 0, 0);
            q = __builtin_amdgcn_mfma_f32_16x16x32_bf16(xa1, wa1, q, 0, 0, 0);
            f32x4 k = __builtin_amdgcn_mfma_f32_16x16x32_bf16(xa0, wb0, (f32x4){0.f,0.f,0.f,0.f}, 0, 0, 0);
            k = __builtin_amdgcn_mfma_f32_16x16x32_bf16(xa1, wb1, k, 0, 0, 0);
            #pragma unroll
            for (int reg = 0; reg < 4; reg++) {
                qab[(drow0 + reg) * 40 + lm] = f2bf(q[reg] + bq_c);
                kbb[(drow0 + reg) * 40 + lm] = f2bf(k[reg] + bk_c);
            }
        }
        // ---- P3: xw = xb * Wd -> xwtb transposed [t][o][v]
        {
            #pragma unroll
            for (int nt = 0; nt < 4; nt++) {
                short8 wd0 = *(const short8*)&wdtg[(nt * 16 + lm) * 72 + kq * 8];
                short8 wd1 = *(const short8*)&wdtg[(nt * 16 + lm) * 72 + 32 + kq * 8];
                f32x4 xw = __builtin_amdgcn_mfma_f32_16x16x32_bf16(xa0, wd0, (f32x4){0.f,0.f,0.f,0.f}, 0, 0, 0);
                xw = __builtin_amdgcn_mfma_f32_16x16x32_bf16(xa1, wd1, xw, 0, 0, 0);
                unsigned short h[4] = {f2bf(xw[0]), f2bf(xw[1]), f2bf(xw[2]), f2bf(xw[3])};
                *(uint2*)&xwtb[t_ * 2560 + (nt * 16 + lm) * 40 + ub] = *(uint2*)h;
            }
        }
        __syncthreads();   // sync_A: kbb (P1->P2, cross-wave), xwtb (P3->P4, cross-wave)

        // ---- P2: E MFMA -> exp -> rowsum(shfl) -> combine -> A_in (into qab, in place)
        {
            short8 aq = *(const short8*)&qab[mrow * 40 + kq * 8];
            short8 bk0 = *(const short8*)&kbb[(t_ * 32 + lm) * 40 + kq * 8];
            short8 bk1 = *(const short8*)&kbb[(t_ * 32 + 16 + lm) * 40 + kq * 8];
            f32x4 e0 = __builtin_amdgcn_mfma_f32_16x16x32_bf16(aq, bk0, (f32x4){0.f,0.f,0.f,0.f}, 0, 0, 0);
            f32x4 e1 = __builtin_amdgcn_mfma_f32_16x16x32_bf16(aq, bk1, (f32x4){0.f,0.f,0.f,0.f}, 0, 0, 0);
            #pragma unroll
            for (int reg = 0; reg < 4; reg++) {
                float p0 = __expf(e0[reg] * 0.25f);
                float p1 = (lm < V - 16) ? __expf(e1[reg] * 0.25f) : 0.f;
                float pr = p0 + p1;
                pr += __shfl_xor(pr, 1);
                pr += __shfl_xor(pr, 2);
                pr += __shfl_xor(pr, 4);
                pr += __shfl_xor(pr, 8);
                float si = w3 / pr;
                int u = ub + reg;
                int uc = (u < V) ? u : 0;
                float a0v = (u < V) ? (acn[uc * 25 + lm] + si * p0) : 0.f;
                float a1v = (u < V && lm < V - 16) ? (acn[uc * 25 + 16 + lm] + si * p1) : 0.f;
                qab[(drow0 + reg) * 40 + lm] = f2bf(a0v);
                qab[(drow0 + reg) * 40 + 16 + lm] = f2bf(a1v);
            }
        }
        // ---- P4: y += A_in * xwtb  (no barrier needed: qab rows wave-private,
        //      xwtb written pre-sync_A)
        {
            short8 aA = *(const short8*)&qab[mrow * 40 + kq * 8];
            #pragma unroll
            for (int nt = 0; nt < 4; nt++) {
                short8 bx8 = *(const short8*)&xwtb[t_ * 2560 + (nt * 16 + lm) * 40 + kq * 8];
                acc[nt] = __builtin_amdgcn_mfma_f32_16x16x32_bf16(aA, bx8, acc[nt], 0, 0, 0);
            }
            // restore qab K-pad zeros for next s's aq read (wave-private rows)
            if (s < S - 1) {
                #pragma unroll
                for (int reg = 0; reg < 4; reg++)
                    qab[(drow0 + reg) * 40 + 16 + lm] = 0;
            }
        }
        __syncthreads();   // sync_B: next-iter P1/P3 overwrite kbb/xwtb
    }

    // ---- epilogue: BN + residual + relu
    if (f32) {
        #pragma unroll
        for (int nt = 0; nt < 4; nt++) {
            int o = nt * 16 + lm;
            float g = gs[o], bt_ = bts[o], bsum = bds[o];
            #pragma unroll
            for (int reg = 0; reg < 4; reg++) {
                int grow = drow0 + reg;
                int t = grow >> 5, u = grow & 31;
                if (u < V) {
                    float xres = b2f(*(const bf16*)&xb[grow * 72 + o]);
                    float yv = fmaxf((acc[nt][reg] + bsum) * g + bt_ + xres, 0.f);
                    size_t ob = (size_t)((n * TT + t0 + t) * V + u) * O + o;
                    ((float*)outp)[ob] = yv;
                }
            }
        }
    } else {
        // stage bf16 results in xwtb (free after last P4 + sync_B), then dump
        // the block's contiguous 6400B output with coalesced 16B stores.
        unsigned short* ep = xwtb;
        #pragma unroll
        for (int nt = 0; nt < 4; nt++) {
            int o = nt * 16 + lm;
            float g = gs[o], bt_ = bts[o], bsum = bds[o];
            #pragma unroll
            for (int reg = 0; reg < 4; reg++) {
                int grow = drow0 + reg;
                int t = grow >> 5, u = grow & 31;
                if (u < V) {
                    float xres = b2f(*(const bf16*)&xb[grow * 72 + o]);
                    float yv = fmaxf((acc[nt][reg] + bsum) * g + bt_ + xres, 0.f);
                    ep[(t * V + u) * O + o] = f2bf(yv);
                }
            }
        }
        __syncthreads();
        uint4* outv = (uint4*)((bf16*)outp + (size_t)(n * TT + t0) * V * O);
        const uint4* epv = (const uint4*)ep;
        for (int w = tid; w < 400; w += 256) outv[w] = epv[w];
    }
}

// ---------------------------------------------------------------------------
extern "C" void kernel_launch(void* const* d_in, const int* in_sizes, int n_in,
                              void* d_out, int out_size, void* d_ws, size_t ws_size,
                              hipStream_t stream) {
    const void* x     = d_in[0];
    const void* A     = d_in[1];
    const void* PA    = d_in[2];
    const void* wA    = d_in[3];
    const void* Wa    = d_in[4];
    const void* ba    = d_in[5];
    const void* Wb    = d_in[6];
    const void* bb    = d_in[7];
    const void* Wd    = d_in[8];
    const void* bd    = d_in[9];
    const void* gamma = d_in[10];
    const void* beta  = d_in[11];

    int*   flagp  = (int*)d_ws;
    float* wsf    = (float*)d_ws;
    float* A_comb = wsf + 64;                         // 1875 f
    float* S1     = wsf + 2048;                       // 60000 f (becomes ac1)
    unsigned short* wprep = (unsigned short*)(wsf + 65536);  // 20736 sh

    k_prep<<<64, 256, 0, stream>>>(x, A, PA, wA, Wa, Wb, Wd, A_comb, S1, wprep, flagp);
    k_s1<<<dim3(TT / TCH, NN, S), 256, 0, stream>>>(x, wprep, ba, bb, S1, flagp);
    k_a1<<<S * NN, 64, 0, stream>>>(S1, A_comb, wA, flagp);
    k_main<<<NN * TT / TB, 256, 0, stream>>>(x, ba, bb, bd, gamma, beta, wA,
                                             wprep, S1, d_out, flagp);
}